// Round 2
// baseline (92.084 us; speedup 1.0000x reference)
//
#include <hip/hip_runtime.h>

#define UNIT_NO 512
#define T_DIM 25
#define K_DIM 20
#define H_DIM 64
#define P_DIM 4096
#define F_DIM 10
#define BATCH 32

// Kernel A: per-unit featurize for units [0, Ustar) only — guaranteed to fit
// in ws_size bytes. Ft[u][f][b] = sum_t S[b][u*25+t]*Wf[u][t][f] + bf[u][f].
// Transposed layout (batch contiguous) so kernel B can stage along b.
__global__ __launch_bounds__(320) void featurize_kernel(
    const float* __restrict__ S, const float* __restrict__ Wf,
    const float* __restrict__ bf, float* __restrict__ Ft)
{
    const int u = blockIdx.x;   // grid = Ustar blocks
    __shared__ float Ws[T_DIM * F_DIM];   // [t][f]
    __shared__ float Ss[BATCH * T_DIM];   // [b][t]
    const int tid = threadIdx.x;
    for (int i = tid; i < T_DIM * F_DIM; i += 320)
        Ws[i] = Wf[u * (T_DIM * F_DIM) + i];
    for (int i = tid; i < BATCH * T_DIM; i += 320) {
        int b = i / T_DIM;
        int t = i - b * T_DIM;
        Ss[i] = S[b * (UNIT_NO * T_DIM) + u * T_DIM + t];
    }
    __syncthreads();
    const int f = tid >> 5;     // 0..9
    const int b = tid & 31;     // 0..31
    float acc = 0.f;
#pragma unroll
    for (int t = 0; t < T_DIM; ++t)
        acc = fmaf(Ss[b * T_DIM + t], Ws[t * F_DIM + f], acc);
    Ft[(u * F_DIM + f) * BATCH + b] = acc + bf[u * F_DIM + f];
}

// Kernel B: one block per pixel. 4 waves; wave w owns batches [8w, 8w+8), lane = h.
// Units < Ustar stage from Ft (global scratch); units >= Ustar are recomputed
// in-block (block-uniform branch) so correctness never depends on ws_size.
__global__ __launch_bounds__(256) void pixel_kernel(
    const float* __restrict__ Ft, const int* __restrict__ pix_units,
    const float* __restrict__ W1, const float* __restrict__ b1,
    const float* __restrict__ a, const float* __restrict__ Wo,
    const float* __restrict__ bo, float* __restrict__ out,
    const float* __restrict__ S, const float* __restrict__ Wf,
    const float* __restrict__ bf, int Ustar)
{
    const int p = blockIdx.x;
    const int tid = threadIdx.x;
    const int lane = tid & 63;   // h index
    const int wv = tid >> 6;     // batch octet

    __shared__ float Gt[K_DIM * F_DIM][BATCH];  // [k=200][b=32], 25.6 KB
    __shared__ int us[K_DIM];

    if (tid < K_DIM) us[tid] = pix_units[p * K_DIM + tid];
    __syncthreads();

    // Stage gathered features: Gt[j*10+f][b] = F[us[j]][f][b]
    for (int j = 0; j < K_DIM; ++j) {
        const int u = us[j];               // block-uniform
        if (u < Ustar) {
            // fast path: coalesced copy from Ft
            for (int o = tid; o < F_DIM * BATCH; o += 256) {
                int f = o >> 5, b = o & 31;
                Gt[j * F_DIM + f][b] = Ft[((u * F_DIM + f) << 5) + b];
            }
        } else {
            // recompute path: 25-term dot from L2-resident S, Wf
            for (int o = tid; o < F_DIM * BATCH; o += 256) {
                int f = o >> 5, b = o & 31;
                float acc = bf[u * F_DIM + f];
                const float* __restrict__ sp = S + b * (UNIT_NO * T_DIM) + u * T_DIM;
                const float* __restrict__ wp = Wf + u * (T_DIM * F_DIM) + f;
#pragma unroll
                for (int t = 0; t < T_DIM; ++t)
                    acc = fmaf(sp[t], wp[t * F_DIM], acc);
                Gt[j * F_DIM + f][b] = acc;
            }
        }
    }
    __syncthreads();

    const float* __restrict__ w1p = W1 + (size_t)p * (K_DIM * F_DIM * H_DIM) + lane;
    const float* __restrict__ gk = &Gt[0][wv * 8];

    float acc[8];
#pragma unroll
    for (int i = 0; i < 8; ++i) acc[i] = 0.f;

#pragma unroll 8
    for (int k = 0; k < K_DIM * F_DIM; ++k) {
        float w1 = w1p[k * H_DIM];                         // coalesced 256B/wave stream
        float4 g0 = *(const float4*)(gk + k * BATCH);      // broadcast ds_read_b128
        float4 g1 = *(const float4*)(gk + k * BATCH + 4);  // broadcast ds_read_b128
        acc[0] = fmaf(g0.x, w1, acc[0]);
        acc[1] = fmaf(g0.y, w1, acc[1]);
        acc[2] = fmaf(g0.z, w1, acc[2]);
        acc[3] = fmaf(g0.w, w1, acc[3]);
        acc[4] = fmaf(g1.x, w1, acc[4]);
        acc[5] = fmaf(g1.y, w1, acc[5]);
        acc[6] = fmaf(g1.z, w1, acc[6]);
        acc[7] = fmaf(g1.w, w1, acc[7]);
    }

    // Epilogue: bias, PReLU, dot with Wo, reduce over h (64 lanes)
    const float b1v = b1[p * H_DIM + lane];
    const float av  = a[p];
    const float wov = Wo[p * H_DIM + lane];
    float s[8];
#pragma unroll
    for (int i = 0; i < 8; ++i) {
        float h = acc[i] + b1v;
        h = (h >= 0.f) ? h : av * h;
        s[i] = h * wov;
    }
#pragma unroll
    for (int off = 32; off > 0; off >>= 1) {
#pragma unroll
        for (int i = 0; i < 8; ++i) s[i] += __shfl_down(s[i], off);
    }
    if (lane == 0) {
        const float bov = bo[p];
#pragma unroll
        for (int i = 0; i < 8; ++i)
            out[(size_t)(wv * 8 + i) * P_DIM + p] = s[i] + bov;
    }
}

extern "C" void kernel_launch(void* const* d_in, const int* in_sizes, int n_in,
                              void* d_out, int out_size, void* d_ws, size_t ws_size,
                              hipStream_t stream) {
    const float* S         = (const float*)d_in[0];
    const int*   pix_units = (const int*)d_in[1];
    const float* Wf        = (const float*)d_in[2];
    const float* bf        = (const float*)d_in[3];
    const float* W1        = (const float*)d_in[4];
    const float* b1        = (const float*)d_in[5];
    const float* a         = (const float*)d_in[6];
    const float* Wo        = (const float*)d_in[7];
    const float* bo        = (const float*)d_in[8];
    float* out = (float*)d_out;
    float* Ft  = (float*)d_ws;

    // Number of units whose [10][32] fp32 feature tile fits in ws_size.
    // Deterministic (depends only on ws_size). Never writes beyond d_ws.
    int Ustar = (int)(ws_size / (size_t)(F_DIM * BATCH * sizeof(float)));
    if (Ustar > UNIT_NO) Ustar = UNIT_NO;

    if (Ustar > 0)
        featurize_kernel<<<Ustar, 320, 0, stream>>>(S, Wf, bf, Ft);
    pixel_kernel<<<P_DIM, 256, 0, stream>>>(Ft, pix_units, W1, b1, a, Wo, bo, out,
                                            S, Wf, bf, Ustar);
}

// Round 3
// 75.224 us; speedup vs baseline: 1.2241x; 1.2241x over previous
//
#include <hip/hip_runtime.h>

#define UNIT_NO 512
#define T_DIM 25
#define K_DIM 20
#define H_DIM 64
#define P_DIM 4096
#define F_DIM 10
#define BATCH 32
#define KTOT (K_DIM * F_DIM)   // 200
#define GT_LD 36               // padded LDS row stride (floats); 144B, 16B-aligned

// Kernel A: per-unit featurize for units [0, Ustar). Ft[u][f][b], batch contiguous.
__global__ __launch_bounds__(320) void featurize_kernel(
    const float* __restrict__ S, const float* __restrict__ Wf,
    const float* __restrict__ bf, float* __restrict__ Ft)
{
    const int u = blockIdx.x;
    __shared__ float Ws[T_DIM * F_DIM];   // [t][f]
    __shared__ float Ss[BATCH * T_DIM];   // [b][t]
    const int tid = threadIdx.x;
    for (int i = tid; i < T_DIM * F_DIM; i += 320)
        Ws[i] = Wf[u * (T_DIM * F_DIM) + i];
    for (int i = tid; i < BATCH * T_DIM; i += 320) {
        int b = i / T_DIM;
        int t = i - b * T_DIM;
        Ss[i] = S[b * (UNIT_NO * T_DIM) + u * T_DIM + t];
    }
    __syncthreads();
    const int f = tid >> 5;     // 0..9
    const int b = tid & 31;     // 0..31
    float acc = 0.f;
#pragma unroll
    for (int t = 0; t < T_DIM; ++t)
        acc = fmaf(Ss[b * T_DIM + t], Ws[t * F_DIM + f], acc);
    Ft[(u * F_DIM + f) * BATCH + b] = acc + bf[u * F_DIM + f];
}

#define FMA8(hh, wc)                                  \
    acc[hh][0] = fmaf(wc, g0.x, acc[hh][0]);          \
    acc[hh][1] = fmaf(wc, g0.y, acc[hh][1]);          \
    acc[hh][2] = fmaf(wc, g0.z, acc[hh][2]);          \
    acc[hh][3] = fmaf(wc, g0.w, acc[hh][3]);          \
    acc[hh][4] = fmaf(wc, g1.x, acc[hh][4]);          \
    acc[hh][5] = fmaf(wc, g1.y, acc[hh][5]);          \
    acc[hh][6] = fmaf(wc, g1.z, acc[hh][6]);          \
    acc[hh][7] = fmaf(wc, g1.w, acc[hh][7]);

// Kernel B: one block per pixel; 4 waves; wave wv owns batches [8wv, 8wv+8).
// Lane split: h0 = (lane&15)*4 (4 h's via dwordx4), kq = lane>>4 (k phase mod 4).
__global__ __launch_bounds__(256, 4) void pixel_kernel(
    const float* __restrict__ Ft, const int* __restrict__ pix_units,
    const float* __restrict__ W1, const float* __restrict__ b1,
    const float* __restrict__ a, const float* __restrict__ Wo,
    const float* __restrict__ bo, float* __restrict__ out,
    const float* __restrict__ S, const float* __restrict__ Wf,
    const float* __restrict__ bf, int Ustar)
{
    const int p = blockIdx.x;
    const int tid = threadIdx.x;
    const int lane = tid & 63;
    const int wv = tid >> 6;

    __shared__ float Gt[KTOT][GT_LD];   // 200 x 36 floats = 28.8 KB
    __shared__ int us[K_DIM];

    if (tid < K_DIM) us[tid] = pix_units[p * K_DIM + tid];
    __syncthreads();

    // Stage gathered features as float4: Gt[j*10+f][b] = F[us[j]][f][b]
    for (int o4 = tid; o4 < KTOT * (BATCH / 4); o4 += 256) {  // 1600 float4s
        const int r  = o4 >> 3;       // row 0..199
        const int b4 = o4 & 7;        // float4 slot in row
        const int j  = r / F_DIM;
        const int f  = r - j * F_DIM;
        const int u  = us[j];
        float4 v;
        if (u < Ustar) {
            v = *(const float4*)(Ft + ((u * F_DIM + f) << 5) + (b4 << 2));
        } else {
            float vv[4];
#pragma unroll
            for (int q = 0; q < 4; ++q) {
                const int b = (b4 << 2) + q;
                float acc = bf[u * F_DIM + f];
                const float* __restrict__ sp = S + b * (UNIT_NO * T_DIM) + u * T_DIM;
                const float* __restrict__ wp = Wf + u * (T_DIM * F_DIM) + f;
#pragma unroll
                for (int t = 0; t < T_DIM; ++t)
                    vv[q] = acc = fmaf(sp[t], wp[t * F_DIM], acc);
            }
            v = make_float4(vv[0], vv[1], vv[2], vv[3]);
        }
        *(float4*)(&Gt[r][b4 << 2]) = v;
    }
    __syncthreads();

    const int kq = lane >> 4;          // k phase 0..3
    const int h0 = (lane & 15) << 2;   // h base 0..60

    const float* __restrict__ w1p =
        W1 + (size_t)p * (KTOT * H_DIM) + kq * H_DIM + h0;
    const float* __restrict__ gkp = &Gt[kq][wv * 8];

    float acc[4][8];
#pragma unroll
    for (int hh = 0; hh < 4; ++hh)
#pragma unroll
        for (int i = 0; i < 8; ++i) acc[hh][i] = 0.f;

    // k = 4*kg + kq; per iter: 1 dwordx4 (coalesced 1KB/wave), 2 broadcast b128, 32 FMA
#pragma unroll 5
    for (int kg = 0; kg < KTOT / 4; ++kg) {
        const float4 w  = *(const float4*)(w1p + kg * (4 * H_DIM));
        const float* g  = gkp + kg * (4 * GT_LD);
        const float4 g0 = *(const float4*)(g);
        const float4 g1 = *(const float4*)(g + 4);
        FMA8(0, w.x)
        FMA8(1, w.y)
        FMA8(2, w.z)
        FMA8(3, w.w)
    }

    // Combine the 4 k-phases: lanes l, l^16, l^32, l^48 hold disjoint k-subsets.
#pragma unroll
    for (int hh = 0; hh < 4; ++hh)
#pragma unroll
        for (int i = 0; i < 8; ++i) {
            float v = acc[hh][i];
            v += __shfl_xor(v, 16);
            v += __shfl_xor(v, 32);
            acc[hh][i] = v;
        }

    // Epilogue: bias + PReLU + Wo dot over this lane's 4 h's
    const float4 b1v = *(const float4*)(b1 + p * H_DIM + h0);
    const float4 wov = *(const float4*)(Wo + p * H_DIM + h0);
    const float av = a[p];
    float s[8];
#pragma unroll
    for (int i = 0; i < 8; ++i) {
        float v0 = acc[0][i] + b1v.x; v0 = (v0 >= 0.f) ? v0 : av * v0;
        float v1 = acc[1][i] + b1v.y; v1 = (v1 >= 0.f) ? v1 : av * v1;
        float v2 = acc[2][i] + b1v.z; v2 = (v2 >= 0.f) ? v2 : av * v2;
        float v3 = acc[3][i] + b1v.w; v3 = (v3 >= 0.f) ? v3 : av * v3;
        s[i] = fmaf(v0, wov.x, fmaf(v1, wov.y, fmaf(v2, wov.z, v3 * wov.w)));
    }
    // Sum over the 16 h-groups
#pragma unroll
    for (int off = 1; off < 16; off <<= 1)
#pragma unroll
        for (int i = 0; i < 8; ++i) s[i] += __shfl_xor(s[i], off);

    if (lane == 0) {
        const float bov = bo[p];
#pragma unroll
        for (int i = 0; i < 8; ++i)
            out[(size_t)(wv * 8 + i) * P_DIM + p] = s[i] + bov;
    }
}

extern "C" void kernel_launch(void* const* d_in, const int* in_sizes, int n_in,
                              void* d_out, int out_size, void* d_ws, size_t ws_size,
                              hipStream_t stream) {
    const float* S         = (const float*)d_in[0];
    const int*   pix_units = (const int*)d_in[1];
    const float* Wf        = (const float*)d_in[2];
    const float* bf        = (const float*)d_in[3];
    const float* W1        = (const float*)d_in[4];
    const float* b1        = (const float*)d_in[5];
    const float* a         = (const float*)d_in[6];
    const float* Wo        = (const float*)d_in[7];
    const float* bo        = (const float*)d_in[8];
    float* out = (float*)d_out;
    float* Ft  = (float*)d_ws;

    // Units whose [10][32] fp32 tile fits in ws_size; rest recomputed in-block.
    int Ustar = (int)(ws_size / (size_t)(F_DIM * BATCH * sizeof(float)));
    if (Ustar > UNIT_NO) Ustar = UNIT_NO;

    if (Ustar > 0)
        featurize_kernel<<<Ustar, 320, 0, stream>>>(S, Wf, bf, Ft);
    pixel_kernel<<<P_DIM, 256, 0, stream>>>(Ft, pix_units, W1, b1, a, Wo, bo, out,
                                            S, Wf, bf, Ustar);
}